// Round 1
// 1156.452 us; speedup vs baseline: 1.0997x; 1.0997x over previous
//
#include <hip/hip_runtime.h>

typedef __bf16 bf16;
typedef __bf16 bf16x8 __attribute__((ext_vector_type(8)));
typedef float f32x4 __attribute__((ext_vector_type(4)));

constexpr int kB = 64;
constexpr int kS = 2048;
constexpr int kD = 1024;          // decoder size (N of main GEMM)
constexpr int kM = 1024;          // memory size  (K of main GEMM)
constexpr int kRows = kB * kS;    // 131072

__device__ __forceinline__ void async_copy16(const void* gsrc, void* ldst) {
    __builtin_amdgcn_global_load_lds(
        (const __attribute__((address_space(1))) void*)gsrc,
        (__attribute__((address_space(3))) void*)ldst, 16, 0, 0);
}

__device__ __forceinline__ float fast_tanh(float x) {
    // tanh(x) = 1 - 2/(exp(2x)+1); exp->v_exp_f32, rcp->v_rcp_f32.
    float e = __expf(2.0f * x);
    return 1.0f - 2.0f * __builtin_amdgcn_rcpf(e + 1.0f);
}

// ---------------------------------------------------------------------------
// P1: WT[d][m] = bf16(W_mem[m][d])  (transpose+cast so B-frag staging is linear)
__global__ __launch_bounds__(256) void wmem_transpose_kernel(
    const float* __restrict__ Wm, bf16* __restrict__ WT) {
    int idx = blockIdx.x * 256 + threadIdx.x;   // 1M threads
    int d = idx >> 10, m = idx & 1023;
    WT[idx] = (bf16)Wm[m * 1024 + d];
}

// ---------------------------------------------------------------------------
// P2: dec_feat[b][d] = sum_m dec[b][m] * W_dec[m][d]   (tiny fp32 GEMM)
__global__ __launch_bounds__(256) void dec_project_kernel(
    const float* __restrict__ dec, const float* __restrict__ Wd,
    float* __restrict__ decf) {
    const int b = blockIdx.x;
    const int d = blockIdx.y * 256 + threadIdx.x;
    const float* drow = dec + b * kD;
    float acc = 0.f;
    #pragma unroll 8
    for (int m = 0; m < kM; ++m)
        acc += drow[m] * Wd[(size_t)m * kD + d];
    decf[b * kD + d] = acc;
}

// ---------------------------------------------------------------------------
// A: fused  E = MB @ W_mem ; partial_score = sum_d tanh(E + decf) * Wv
// 128x256 tile, 512 threads / 8 waves (2x4), wave tile 64x64 (4x4 of 16x16x32).
// BN=256 halves structural A traffic vs BN=128 (4 col-tiles per row, not 8),
// and the XCD remap puts all 4 col-tiles of a row on ONE XCD so 3 of 4 A-panel
// reads are L2 hits instead of fresh HBM/L3 fills.
constexpr int BM = 128, BN = 256, BK = 32, APAD = 40;
constexpr int NCOL = kD / BN;   // 4

__global__ __launch_bounds__(512, 4) void attn_scores_kernel(
    const float* __restrict__ MBank,   // [kRows, kM] fp32
    const bf16*  __restrict__ WT,      // [kD, kM]   bf16 (W_mem transposed)
    const float* __restrict__ decf,    // [kB, kD]
    const float* __restrict__ Wv,      // [kD]
    float* __restrict__ spart)         // [NCOL][kRows]
{
    __shared__ bf16 Atile[BM * APAD];   // 10240 B (rows padded: 80B, conflict-light)
    __shared__ bf16 Btile[BN * BK];     // 16384 B [n][k] stride 32 (global_load_lds layout)
    __shared__ float sred[BM * 4];      // 2048 B

    const int tid  = threadIdx.x;
    const int wave = tid >> 6;          // 0..7
    const int lane = tid & 63;
    const int ln   = lane & 15;
    const int quad = lane >> 4;

    // ---- XCD-aware remap: linear id L; XCD = L%8 (dispatch round-robin).
    // Each XCD owns a contiguous range of 128 row tiles; its 4 col-tile
    // blocks per row are adjacent in launch order -> A panel shared in L2.
    const int L = blockIdx.y * NCOL + blockIdx.x;      // 0..4095
    const int jw = L >> 3;                             // 0..511
    const int rowTile = ((L & 7) << 7) + (jw >> 2);    // 0..1023
    const int colTile = jw & 3;                        // 0..3
    const int R0 = rowTile * BM;
    const int C0 = colTile * BN;
    const int batch = rowTile >> 4;     // 128 rows always inside one batch

    const int wr = (wave >> 2) * 64;    // 0 or 64
    const int wc = (wave & 3) * 64;     // 0,64,128,192

    const int arow  = tid >> 2;         // 0..127
    const int akseg = (tid & 3) * 8;    // 0,8,16,24
    const float* aptr = MBank + (size_t)(R0 + arow) * kM + akseg;

    f32x4 acc[4][4];
    const f32x4 zero = {0.f, 0.f, 0.f, 0.f};
    #pragma unroll
    for (int i = 0; i < 4; ++i)
        #pragma unroll
        for (int j = 0; j < 4; ++j)
            acc[i][j] = zero;

    for (int k0 = 0; k0 < kM; k0 += BK) {
        __syncthreads();
        // ---- stage B (bf16, pre-transposed): 16 async 1KB chunks direct-to-LDS
        #pragma unroll
        for (int jj = 0; jj < 2; ++jj) {
            const int chunk = wave * 2 + jj;             // 0..15
            const int n = chunk * 16 + (lane >> 2);
            async_copy16(WT + (size_t)(C0 + n) * kM + k0 + (lane & 3) * 8,
                         Btile + chunk * 512);
        }
        // ---- stage A: fp32 global -> RTNE bf16 -> LDS (padded rows)
        {
            const float* ap = aptr + k0;
            f32x4 v0 = *(const f32x4*)(ap + 0);
            f32x4 v1 = *(const f32x4*)(ap + 4);
            bf16x8 w0;
            w0[0]=(bf16)v0[0]; w0[1]=(bf16)v0[1]; w0[2]=(bf16)v0[2]; w0[3]=(bf16)v0[3];
            w0[4]=(bf16)v1[0]; w0[5]=(bf16)v1[1]; w0[6]=(bf16)v1[2]; w0[7]=(bf16)v1[3];
            *(bf16x8*)(Atile + arow * APAD + akseg) = w0;
        }
        __syncthreads();

        // ---- compute: 8 ds_read_b128 + 16 MFMA per wave
        bf16x8 af[4], bfr[4];
        #pragma unroll
        for (int i = 0; i < 4; ++i)
            af[i] = *(const bf16x8*)(Atile + (wr + i * 16 + ln) * APAD + quad * 8);
        #pragma unroll
        for (int j = 0; j < 4; ++j)
            bfr[j] = *(const bf16x8*)(Btile + (wc + j * 16 + ln) * BK + quad * 8);
        #pragma unroll
        for (int i = 0; i < 4; ++i)
            #pragma unroll
            for (int j = 0; j < 4; ++j)
                acc[i][j] = __builtin_amdgcn_mfma_f32_16x16x32_bf16(
                    af[i], bfr[j], acc[i][j], 0, 0, 0);
    }

    // ---- epilogue: tanh(E+decf)*Wv, reduce over this block's 256 cols
    float wv[4], df[4];
    #pragma unroll
    for (int j = 0; j < 4; ++j) {
        const int d = C0 + wc + j * 16 + ln;
        wv[j] = Wv[d];
        df[j] = decf[batch * kD + d];
    }
    float rp[4][4];
    #pragma unroll
    for (int i = 0; i < 4; ++i) {
        #pragma unroll
        for (int r = 0; r < 4; ++r) {
            float p = 0.f;
            #pragma unroll
            for (int j = 0; j < 4; ++j) {
                float x = acc[i][j][r] + df[j];   // C/D: row=quad*4+r, col=ln
                p += fast_tanh(x) * wv[j];
            }
            #pragma unroll
            for (int off = 1; off < 16; off <<= 1)
                p += __shfl_xor(p, off, 64);      // sum over 16 cols in the quad
            rp[i][r] = p;
        }
    }
    if (ln == 0) {
        #pragma unroll
        for (int i = 0; i < 4; ++i)
            #pragma unroll
            for (int r = 0; r < 4; ++r)
                sred[(wr + i * 16 + quad * 4 + r) * 4 + (wave & 3)] = rp[i][r];
    }
    __syncthreads();
    if (tid < BM)
        spart[(size_t)colTile * kRows + R0 + tid] =
            (sred[tid * 4 + 0] + sred[tid * 4 + 1]) +
            (sred[tid * 4 + 2] + sred[tid * 4 + 3]);
}

// ---------------------------------------------------------------------------
// B: softmax over S per batch; writes attn_dist (fp32) to d_out+65536
__global__ __launch_bounds__(256) void softmax_kernel(
    const float* __restrict__ spart, const int* __restrict__ mask,
    float* __restrict__ attn) {
    const int b = blockIdx.x;
    const int tid = threadIdx.x;
    __shared__ float sc[kS];
    __shared__ float redm[4], reds[4];

    float lmax = -INFINITY;
    for (int s = tid; s < kS; s += 256) {
        float v = 0.f;
        #pragma unroll
        for (int t = 0; t < NCOL; ++t) v += spart[(size_t)t * kRows + b * kS + s];
        if (mask[b * kS + s] == 0) v = -INFINITY;
        sc[s] = v;
        lmax = fmaxf(lmax, v);
    }
    #pragma unroll
    for (int off = 32; off; off >>= 1) lmax = fmaxf(lmax, __shfl_xor(lmax, off, 64));
    if ((tid & 63) == 0) redm[tid >> 6] = lmax;
    __syncthreads();
    const float bmax = fmaxf(fmaxf(redm[0], redm[1]), fmaxf(redm[2], redm[3]));

    float lsum = 0.f;
    for (int s = tid; s < kS; s += 256) {
        float e = __expf(sc[s] - bmax);
        sc[s] = e;
        lsum += e;
    }
    #pragma unroll
    for (int off = 32; off; off >>= 1) lsum += __shfl_xor(lsum, off, 64);
    if ((tid & 63) == 0) reds[tid >> 6] = lsum;
    __syncthreads();
    const float inv = 1.0f / (reds[0] + reds[1] + reds[2] + reds[3]);
    for (int s = tid; s < kS; s += 256) attn[b * kS + s] = sc[s] * inv;
}

// ---------------------------------------------------------------------------
// C1: context partials over s-chunks (memory-bound streaming of memory_bank)
__global__ __launch_bounds__(256) void ctx_partial_kernel(
    const float* __restrict__ MBank, const float* __restrict__ attn,
    float* __restrict__ cpart) {
    const int b  = blockIdx.x;   // 64
    const int sc = blockIdx.y;   // 16 chunks of 128 s
    const int m4 = threadIdx.x * 4;
    const float* base = MBank + ((size_t)b * kS + sc * 128) * kM + m4;
    const float* ap = attn + b * kS + sc * 128;
    f32x4 acc = {0.f, 0.f, 0.f, 0.f};
    #pragma unroll 4
    for (int s = 0; s < 128; ++s) {
        const float a = ap[s];
        f32x4 v = *(const f32x4*)(base + (size_t)s * kM);
        acc[0] += a * v[0]; acc[1] += a * v[1];
        acc[2] += a * v[2]; acc[3] += a * v[3];
    }
    *(f32x4*)&cpart[((size_t)(b * 16 + sc)) * kM + m4] = acc;
}

// C2: reduce the 16 s-chunk partials -> context
__global__ __launch_bounds__(256) void ctx_reduce_kernel(
    const float* __restrict__ cpart, float* __restrict__ out) {
    const int idx = blockIdx.x * 256 + threadIdx.x;  // 65536
    const int b = idx >> 10, m = idx & 1023;
    float v = 0.f;
    #pragma unroll
    for (int c = 0; c < 16; ++c) v += cpart[(size_t)((b * 16 + c) << 10) + m];
    out[idx] = v;
}

// ---------------------------------------------------------------------------
extern "C" void kernel_launch(void* const* d_in, const int* in_sizes, int n_in,
                              void* d_out, int out_size, void* d_ws, size_t ws_size,
                              hipStream_t stream) {
    const float* dec   = (const float*)d_in[0];   // [64,1024]
    const float* MBank = (const float*)d_in[1];   // [64,2048,1024]
    const int*   mask  = (const int*)d_in[2];     // [64,2048]
    const float* Wv    = (const float*)d_in[3];   // [1024]
    const float* Wdec  = (const float*)d_in[4];   // [1024,1024]
    const float* Wmem  = (const float*)d_in[5];   // [1024,1024]

    float* out_ctx  = (float*)d_out;              // 65536 floats
    float* out_attn = (float*)d_out + kB * kD;    // 131072 floats

    char* ws = (char*)d_ws;
    bf16*  WT    = (bf16*)ws;                                   // 2 MB
    float* decf  = (float*)(ws + (1 << 21));                    // 256 KB
    float* spart = (float*)(ws + (1 << 21) + (1 << 18));        // 2 MB (4 slices)
    float* cpart = (float*)(ws + (1 << 21) + (1 << 18) + (1 << 21)); // 4 MB

    wmem_transpose_kernel<<<4096, 256, 0, stream>>>(Wmem, WT);
    dec_project_kernel<<<dim3(64, 4), 256, 0, stream>>>(dec, Wdec, decf);
    attn_scores_kernel<<<dim3(NCOL, 1024), 512, 0, stream>>>(MBank, WT, decf, Wv, spart);
    softmax_kernel<<<64, 256, 0, stream>>>(spart, mask, out_attn);
    ctx_partial_kernel<<<dim3(64, 16), 256, 0, stream>>>(MBank, out_attn, cpart);
    ctx_reduce_kernel<<<256, 256, 0, stream>>>(cpart, out_ctx);
}

// Round 2
// 1135.450 us; speedup vs baseline: 1.1200x; 1.0185x over previous
//
#include <hip/hip_runtime.h>

typedef __bf16 bf16;
typedef __bf16 bf16x8 __attribute__((ext_vector_type(8)));
typedef float f32x4 __attribute__((ext_vector_type(4)));

constexpr int kB = 64;
constexpr int kS = 2048;
constexpr int kD = 1024;          // decoder size (N of main GEMM)
constexpr int kM = 1024;          // memory size  (K of main GEMM)
constexpr int kRows = kB * kS;    // 131072

__device__ __forceinline__ void async_copy16(const void* gsrc, void* ldst) {
    __builtin_amdgcn_global_load_lds(
        (const __attribute__((address_space(1))) void*)gsrc,
        (__attribute__((address_space(3))) void*)ldst, 16, 0, 0);
}

__device__ __forceinline__ float fast_tanh(float x) {
    // tanh(x) = 1 - 2/(exp(2x)+1); exp->v_exp_f32, rcp->v_rcp_f32.
    float e = __expf(2.0f * x);
    return 1.0f - 2.0f * __builtin_amdgcn_rcpf(e + 1.0f);
}

// ---------------------------------------------------------------------------
// P1: WT[d][m] = bf16(W_mem[m][d]) — LDS-tiled transpose, coalesced both sides.
__global__ __launch_bounds__(256) void wmem_transpose_kernel(
    const float* __restrict__ Wm, bf16* __restrict__ WT) {
    __shared__ bf16 tile[64][72];            // +8 pad to spread banks
    const int d0 = (blockIdx.x & 15) * 64;
    const int m0 = (blockIdx.x >> 4) * 64;
    const int lane = threadIdx.x & 63;
    const int grp  = threadIdx.x >> 6;       // 0..3
    #pragma unroll
    for (int r = 0; r < 16; ++r) {
        const int m = m0 + grp * 16 + r;
        tile[lane][grp * 16 + r] = (bf16)Wm[m * 1024 + d0 + lane];  // coalesced read
    }
    __syncthreads();
    #pragma unroll
    for (int r = 0; r < 16; ++r) {
        const int d = d0 + grp * 16 + r;
        WT[d * 1024 + m0 + lane] = tile[grp * 16 + r][lane];        // coalesced write
    }
}

// ---------------------------------------------------------------------------
// P2: dec_feat[b][d] = sum_m dec[b][m] * W_dec[m][d]   (tiny fp32 GEMM)
__global__ __launch_bounds__(256) void dec_project_kernel(
    const float* __restrict__ dec, const float* __restrict__ Wd,
    float* __restrict__ decf) {
    const int b = blockIdx.x;
    const int d = blockIdx.y * 256 + threadIdx.x;
    const float* drow = dec + b * kD;
    float acc = 0.f;
    #pragma unroll 8
    for (int m = 0; m < kM; ++m)
        acc += drow[m] * Wd[(size_t)m * kD + d];
    decf[b * kD + d] = acc;
}

// ---------------------------------------------------------------------------
// A: fused  E = MB @ W_mem ; partial_score = sum_d tanh(E + decf) * Wv
// 128x256 tile, 512 threads / 8 waves (2x4), wave tile 64x64 (4x4 of 16x16x32).
// v2: double-buffered 2-phase pipeline — ONE barrier per K-step, next tile's
// A-loads (regs) and B global_load_lds issued before the MFMA cluster so the
// global latency hides under compute (T3-minimal + T14 split).
constexpr int BM = 128, BN = 256, BK = 32, APAD = 40;
constexpr int NCOL = kD / BN;   // 4
constexpr int NSTEP = kM / BK;  // 32

__global__ __launch_bounds__(512, 4) void attn_scores_kernel(
    const float* __restrict__ MBank,   // [kRows, kM] fp32
    const bf16*  __restrict__ WT,      // [kD, kM]   bf16 (W_mem transposed)
    const float* __restrict__ decf,    // [kB, kD]
    const float* __restrict__ Wv,      // [kD]
    float* __restrict__ spart)         // [NCOL][kRows]
{
    __shared__ bf16 Abuf[2][BM * APAD];  // 2 x 10240 B
    __shared__ bf16 Bbuf[2][BN * BK];    // 2 x 16384 B
    __shared__ float sred[BM * 4];       // 2048 B

    const int tid  = threadIdx.x;
    const int wave = tid >> 6;          // 0..7
    const int lane = tid & 63;
    const int ln   = lane & 15;
    const int quad = lane >> 4;

    // ---- XCD-aware remap: linear id L; XCD = L%8 (dispatch round-robin).
    const int L = blockIdx.y * NCOL + blockIdx.x;      // 0..4095
    const int jw = L >> 3;                             // 0..511
    const int rowTile = ((L & 7) << 7) + (jw >> 2);    // 0..1023
    const int colTile = jw & 3;                        // 0..3
    const int R0 = rowTile * BM;
    const int C0 = colTile * BN;
    const int batch = rowTile >> 4;     // 128 rows always inside one batch

    const int wr = (wave >> 2) * 64;    // 0 or 64
    const int wc = (wave & 3) * 64;     // 0,64,128,192

    const int arow  = tid >> 2;         // 0..127
    const int akseg = (tid & 3) * 8;    // 0,8,16,24
    const float* aptr = MBank + (size_t)(R0 + arow) * kM + akseg;

    // B staging geometry: 16 chunks of 1KB, chunk = wave*2+jj
    const int bn0   = (lane >> 2);          // row within chunk (16 rows)
    const int bkoff = (lane & 3) * 8;       // elem offset within row

    // ---- prologue: stage tile 0 into buf 0
    {
        const float* ap = aptr;
        f32x4 v0 = *(const f32x4*)(ap + 0);
        f32x4 v1 = *(const f32x4*)(ap + 4);
        #pragma unroll
        for (int jj = 0; jj < 2; ++jj) {
            const int chunk = wave * 2 + jj;
            const int n = chunk * 16 + bn0;
            async_copy16(WT + (size_t)(C0 + n) * kM + bkoff,
                         Bbuf[0] + chunk * 512);
        }
        bf16x8 w0;
        w0[0]=(bf16)v0[0]; w0[1]=(bf16)v0[1]; w0[2]=(bf16)v0[2]; w0[3]=(bf16)v0[3];
        w0[4]=(bf16)v1[0]; w0[5]=(bf16)v1[1]; w0[6]=(bf16)v1[2]; w0[7]=(bf16)v1[3];
        *(bf16x8*)(Abuf[0] + arow * APAD + akseg) = w0;
    }
    __syncthreads();

    f32x4 acc[4][4];
    const f32x4 zero = {0.f, 0.f, 0.f, 0.f};
    #pragma unroll
    for (int i = 0; i < 4; ++i)
        #pragma unroll
        for (int j = 0; j < 4; ++j)
            acc[i][j] = zero;

    #pragma unroll 2
    for (int t = 0; t < NSTEP; ++t) {
        const int cur = t & 1, nxt = cur ^ 1;
        const bool pf = (t + 1 < NSTEP);
        const int k1 = (t + 1) * BK;

        // ---- issue next tile's loads FIRST (A regs first, so the cvt below
        //      waits only on A — vmcnt(2) — while B's gll stays in flight)
        f32x4 v0, v1;
        if (pf) {
            const float* ap = aptr + k1;
            v0 = *(const f32x4*)(ap + 0);
            v1 = *(const f32x4*)(ap + 4);
            #pragma unroll
            for (int jj = 0; jj < 2; ++jj) {
                const int chunk = wave * 2 + jj;
                const int n = chunk * 16 + bn0;
                async_copy16(WT + (size_t)(C0 + n) * kM + k1 + bkoff,
                             Bbuf[nxt] + chunk * 512);
            }
        }

        // ---- compute current tile: 8 ds_read_b128 + 16 MFMA per wave
        const bf16* Ac = Abuf[cur];
        const bf16* Bc = Bbuf[cur];
        bf16x8 af[4], bfr[4];
        #pragma unroll
        for (int i = 0; i < 4; ++i)
            af[i] = *(const bf16x8*)(Ac + (wr + i * 16 + ln) * APAD + quad * 8);
        #pragma unroll
        for (int j = 0; j < 4; ++j)
            bfr[j] = *(const bf16x8*)(Bc + (wc + j * 16 + ln) * BK + quad * 8);
        __builtin_amdgcn_s_setprio(1);
        #pragma unroll
        for (int i = 0; i < 4; ++i)
            #pragma unroll
            for (int j = 0; j < 4; ++j)
                acc[i][j] = __builtin_amdgcn_mfma_f32_16x16x32_bf16(
                    af[i], bfr[j], acc[i][j], 0, 0, 0);
        __builtin_amdgcn_s_setprio(0);

        // ---- finish A prefetch: cvt + ds_write into the other buffer
        if (pf) {
            bf16x8 w0;
            w0[0]=(bf16)v0[0]; w0[1]=(bf16)v0[1]; w0[2]=(bf16)v0[2]; w0[3]=(bf16)v0[3];
            w0[4]=(bf16)v1[0]; w0[5]=(bf16)v1[1]; w0[6]=(bf16)v1[2]; w0[7]=(bf16)v1[3];
            *(bf16x8*)(Abuf[nxt] + arow * APAD + akseg) = w0;
        }
        __syncthreads();   // single barrier per K-step (drains vmcnt+lgkm)
    }

    // ---- epilogue: tanh(E+decf)*Wv, reduce over this block's 256 cols
    float wv[4], df[4];
    #pragma unroll
    for (int j = 0; j < 4; ++j) {
        const int d = C0 + wc + j * 16 + ln;
        wv[j] = Wv[d];
        df[j] = decf[batch * kD + d];
    }
    float rp[4][4];
    #pragma unroll
    for (int i = 0; i < 4; ++i) {
        #pragma unroll
        for (int r = 0; r < 4; ++r) {
            float p = 0.f;
            #pragma unroll
            for (int j = 0; j < 4; ++j) {
                float x = acc[i][j][r] + df[j];   // C/D: row=quad*4+r, col=ln
                p += fast_tanh(x) * wv[j];
            }
            #pragma unroll
            for (int off = 1; off < 16; off <<= 1)
                p += __shfl_xor(p, off, 64);      // sum over 16 cols in the quad
            rp[i][r] = p;
        }
    }
    if (ln == 0) {
        #pragma unroll
        for (int i = 0; i < 4; ++i)
            #pragma unroll
            for (int r = 0; r < 4; ++r)
                sred[(wr + i * 16 + quad * 4 + r) * 4 + (wave & 3)] = rp[i][r];
    }
    __syncthreads();
    if (tid < BM)
        spart[(size_t)colTile * kRows + R0 + tid] =
            (sred[tid * 4 + 0] + sred[tid * 4 + 1]) +
            (sred[tid * 4 + 2] + sred[tid * 4 + 3]);
}

// ---------------------------------------------------------------------------
// B: softmax over S per batch; writes attn_dist (fp32) to d_out+65536
__global__ __launch_bounds__(256) void softmax_kernel(
    const float* __restrict__ spart, const int* __restrict__ mask,
    float* __restrict__ attn) {
    const int b = blockIdx.x;
    const int tid = threadIdx.x;
    __shared__ float sc[kS];
    __shared__ float redm[4], reds[4];

    float lmax = -INFINITY;
    for (int s = tid; s < kS; s += 256) {
        float v = 0.f;
        #pragma unroll
        for (int t = 0; t < NCOL; ++t) v += spart[(size_t)t * kRows + b * kS + s];
        if (mask[b * kS + s] == 0) v = -INFINITY;
        sc[s] = v;
        lmax = fmaxf(lmax, v);
    }
    #pragma unroll
    for (int off = 32; off; off >>= 1) lmax = fmaxf(lmax, __shfl_xor(lmax, off, 64));
    if ((tid & 63) == 0) redm[tid >> 6] = lmax;
    __syncthreads();
    const float bmax = fmaxf(fmaxf(redm[0], redm[1]), fmaxf(redm[2], redm[3]));

    float lsum = 0.f;
    for (int s = tid; s < kS; s += 256) {
        float e = __expf(sc[s] - bmax);
        sc[s] = e;
        lsum += e;
    }
    #pragma unroll
    for (int off = 32; off; off >>= 1) lsum += __shfl_xor(lsum, off, 64);
    if ((tid & 63) == 0) reds[tid >> 6] = lsum;
    __syncthreads();
    const float inv = 1.0f / (reds[0] + reds[1] + reds[2] + reds[3]);
    for (int s = tid; s < kS; s += 256) attn[b * kS + s] = sc[s] * inv;
}

// ---------------------------------------------------------------------------
// C1: context partials over s-chunks. v2: dual accumulator chains + paired
// loads so 8x16B loads stay in flight per thread (break the FMA dep chain).
__global__ __launch_bounds__(256) void ctx_partial_kernel(
    const float* __restrict__ MBank, const float* __restrict__ attn,
    float* __restrict__ cpart) {
    const int b  = blockIdx.x;   // 64
    const int sc = blockIdx.y;   // 16 chunks of 128 s
    const int m4 = threadIdx.x * 4;
    const float* base = MBank + ((size_t)b * kS + sc * 128) * kM + m4;
    const float* ap = attn + b * kS + sc * 128;
    f32x4 acc0 = {0.f, 0.f, 0.f, 0.f};
    f32x4 acc1 = {0.f, 0.f, 0.f, 0.f};
    #pragma unroll 4
    for (int s = 0; s < 128; s += 2) {
        const float a0 = ap[s];
        const float a1 = ap[s + 1];
        f32x4 u0 = *(const f32x4*)(base + (size_t)s * kM);
        f32x4 u1 = *(const f32x4*)(base + (size_t)(s + 1) * kM);
        acc0 += u0 * a0;
        acc1 += u1 * a1;
    }
    f32x4 r = acc0 + acc1;
    *(f32x4*)&cpart[((size_t)(b * 16 + sc)) * kM + m4] = r;
}

// C2: reduce the 16 s-chunk partials -> context
__global__ __launch_bounds__(256) void ctx_reduce_kernel(
    const float* __restrict__ cpart, float* __restrict__ out) {
    const int idx = blockIdx.x * 256 + threadIdx.x;  // 65536
    const int b = idx >> 10, m = idx & 1023;
    float v = 0.f;
    #pragma unroll
    for (int c = 0; c < 16; ++c) v += cpart[(size_t)((b * 16 + c) << 10) + m];
    out[idx] = v;
}

// ---------------------------------------------------------------------------
extern "C" void kernel_launch(void* const* d_in, const int* in_sizes, int n_in,
                              void* d_out, int out_size, void* d_ws, size_t ws_size,
                              hipStream_t stream) {
    const float* dec   = (const float*)d_in[0];   // [64,1024]
    const float* MBank = (const float*)d_in[1];   // [64,2048,1024]
    const int*   mask  = (const int*)d_in[2];     // [64,2048]
    const float* Wv    = (const float*)d_in[3];   // [1024]
    const float* Wdec  = (const float*)d_in[4];   // [1024,1024]
    const float* Wmem  = (const float*)d_in[5];   // [1024,1024]

    float* out_ctx  = (float*)d_out;              // 65536 floats
    float* out_attn = (float*)d_out + kB * kD;    // 131072 floats

    char* ws = (char*)d_ws;
    bf16*  WT    = (bf16*)ws;                                   // 2 MB
    float* decf  = (float*)(ws + (1 << 21));                    // 256 KB
    float* spart = (float*)(ws + (1 << 21) + (1 << 18));        // 2 MB (4 slices)
    float* cpart = (float*)(ws + (1 << 21) + (1 << 18) + (1 << 21)); // 4 MB

    wmem_transpose_kernel<<<256, 256, 0, stream>>>(Wmem, WT);
    dec_project_kernel<<<dim3(64, 4), 256, 0, stream>>>(dec, Wdec, decf);
    attn_scores_kernel<<<dim3(NCOL, 1024), 512, 0, stream>>>(MBank, WT, decf, Wv, spart);
    softmax_kernel<<<64, 256, 0, stream>>>(spart, mask, out_attn);
    ctx_partial_kernel<<<dim3(64, 16), 256, 0, stream>>>(MBank, out_attn, cpart);
    ctx_reduce_kernel<<<256, 256, 0, stream>>>(cpart, out_ctx);
}